// Round 25
// baseline (102.074 us; speedup 1.0000x reference)
//
#include <hip/hip_runtime.h>

using short8 = __attribute__((ext_vector_type(8))) short;
using f32x4  = __attribute__((ext_vector_type(4))) float;

__device__ __forceinline__ unsigned short f2bf(float f) {
  unsigned u = __float_as_uint(f);
  u += 0x7fffu + ((u >> 16) & 1u);
  return (unsigned short)(u >> 16);
}

// ---------------- pack W f32 [384k][384c] -> MFMA B-frag blobs wtp[kk 12][ct16 24][lane 64][8] ----------------
__global__ __launch_bounds__(256) void pack_w_kernel(const float* __restrict__ W,
                                                     unsigned short* __restrict__ wtp) {
  const int f = blockIdx.x * 4 + (threadIdx.x >> 6);   // 0..287
  const int l = threadIdx.x & 63;
  const int kk = f / 24, ct = f % 24;
  const int il = l & 15, kg = l >> 4;
  const float* src = W + (size_t)(kk * 32 + kg * 8) * 384 + ct * 16 + il;
  short8 v;
#pragma unroll
  for (int e = 0; e < 8; ++e) v[e] = (short)f2bf(src[(size_t)e * 384]);
  *reinterpret_cast<short8*>((char*)wtp + ((size_t)f << 10) + l * 16) = v;
}

// ---------------- adj int32 -> bitmask [2048][64] words (+ zero f1/f2) ----------------
__global__ __launch_bounds__(256) void adjmask_kernel(const int* __restrict__ adj,
                                                      unsigned* __restrict__ adjm,
                                                      float* __restrict__ f12) {
  if (blockIdx.x < 64) f12[blockIdx.x * 256 + threadIdx.x] = 0.f;   // f1+f2 (16384)
  const int wv = (blockIdx.x << 2) + (threadIdx.x >> 6);
  const int lane = threadIdx.x & 63;
  const int row = wv >> 5, j0 = (wv & 31) << 6;
  unsigned long long mask = __ballot(adj[(size_t)row * 2048 + j0 + lane] > 0);
  if (lane == 0) {
    adjm[row * 64 + (j0 >> 5)]     = (unsigned)mask;
    adjm[row * 64 + (j0 >> 5) + 1] = (unsigned)(mask >> 32);
  }
}

// ---------------- Kernel B: fused conv + Wh GEMM + pack (16x16x32 frags) + f1/f2 ----------------
// grid 1024: b = rb>>8, jg2 = (rb>>1)&127, ch2 = rb&1 (192 cols). 256 thr = 4 waves (48 cols).
// whp[b][js 64][ct16 24][lane 64][8]: lane l elem e = Wh[b][js*32 + (l>>4)*8 + e][ct*16 + (l&15)]
// block jg2 supplies k-half (jg2&1) of js = jg2>>1 -> lanes [(jg2&1)*32, +32)
__global__ __launch_bounds__(256) void gemm_wh5_kernel(const float* __restrict__ x,
                                                       const float* __restrict__ cw,
                                                       const float* __restrict__ cb,
                                                       const unsigned short* __restrict__ wtp,
                                                       const float* __restrict__ a,
                                                       unsigned short* __restrict__ whp,
                                                       float* __restrict__ f1,
                                                       float* __restrict__ f2) {
  __shared__ __align__(16) char lds[24768 + 6400 + 1792];
  float* xin = (float*)lds;                                   // [12][516], 514 used
  unsigned short* atile = (unsigned short*)lds;               // [16][392]
  unsigned short* wtile = (unsigned short*)(lds + 24768);     // [16][200]
  float* cws = (float*)(lds + 24768 + 6400);                  // 432
  float* cbs = cws + 432;                                     // 12

  const int tid = threadIdx.x;
  const int rb = blockIdx.x;
  const int b = rb >> 8;
  const int jg2 = (rb >> 1) & 127;
  const int ch2 = rb & 1;
  const int r0 = ((b << 7) + jg2) << 4;
  const int w = tid >> 6, lane = tid & 63;
  const int il = lane & 15, kg = lane >> 4;

  for (int i = tid; i < 432; i += 256) cws[i] = cw[i];
  if (tid < 12) cbs[tid] = cb[tid];
  const float* xb = x + (size_t)b * 2048 * 12 * 32;
#pragma unroll
  for (int t = 0; t < 12; ++t) {
    for (int i = tid; i < 514; i += 256) {
      const int gp = jg2 * 512 + i - 1;
      float v = 0.f;
      if ((unsigned)gp < 65536u) v = xb[((size_t)(gp >> 5) * 12 + t) * 32 + (gp & 31)];
      xin[t * 516 + i] = v;
    }
  }
  __syncthreads();

  const int ploc = tid * 2;
  float accv0[12], accv1[12];
#pragma unroll
  for (int to = 0; to < 12; ++to) { accv0[to] = cbs[to]; accv1[to] = cbs[to]; }
#pragma unroll
  for (int ti = 0; ti < 12; ++ti) {
    const float x0 = xin[ti * 516 + ploc];
    const float x1 = xin[ti * 516 + ploc + 1];
    const float x2 = xin[ti * 516 + ploc + 2];
    const float x3 = xin[ti * 516 + ploc + 3];
#pragma unroll
    for (int to = 0; to < 12; ++to) {
      const float* wp = &cws[(to * 12 + ti) * 3];
      const float w0 = wp[0], w1 = wp[1], w2 = wp[2];
      accv0[to] += x0 * w0 + x1 * w1 + x2 * w2;
      accv1[to] += x1 * w0 + x2 * w1 + x3 * w2;
    }
  }
  __syncthreads();

  {
    const int row = ploc >> 5, f = ploc & 31;
    unsigned* ap32 = (unsigned*)(atile + row * 392 + f);
#pragma unroll
    for (int to = 0; to < 12; ++to) {
      const unsigned lo = f2bf(accv0[to]), hi = f2bf(accv1[to]);
      ap32[to * 16] = lo | (hi << 16);
    }
  }
  __syncthreads();

  f32x4 acc[3];
#pragma unroll
  for (int t = 0; t < 3; ++t) acc[t] = (f32x4){0.f, 0.f, 0.f, 0.f};
  const unsigned short* arow = atile + il * 392 + kg * 8;
  const int ct0 = ch2 * 12 + w * 3;
  const char* wb = (const char*)wtp + ((size_t)ct0 << 10) + lane * 16;

  short8 bcur[3], bnxt[3];
#pragma unroll
  for (int t = 0; t < 3; ++t)
    bcur[t] = *reinterpret_cast<const short8*>(wb + ((size_t)t << 10));
#pragma unroll
  for (int kk = 0; kk < 12; ++kk) {
    if (kk < 11) {
#pragma unroll
      for (int t = 0; t < 3; ++t)
        bnxt[t] = *reinterpret_cast<const short8*>(wb + (((size_t)(kk + 1) * 24 + t) << 10));
    }
    short8 af = *reinterpret_cast<const short8*>(arow + kk * 32);
#pragma unroll
    for (int t = 0; t < 3; ++t)
      acc[t] = __builtin_amdgcn_mfma_f32_16x16x32_bf16(af, bcur[t], acc[t], 0, 0, 0);
#pragma unroll
    for (int t = 0; t < 3; ++t) bcur[t] = bnxt[t];
  }

  float p1[4] = {0.f, 0.f, 0.f, 0.f}, p2[4] = {0.f, 0.f, 0.f, 0.f};
#pragma unroll
  for (int t = 0; t < 3; ++t) {
    const int c = (ct0 + t) * 16 + il;
    const float a1v = a[c], a2v = a[384 + c];
#pragma unroll
    for (int r = 0; r < 4; ++r) { p1[r] += acc[t][r] * a1v; p2[r] += acc[t][r] * a2v; }
  }
#pragma unroll
  for (int off = 1; off < 16; off <<= 1) {
#pragma unroll
    for (int r = 0; r < 4; ++r) { p1[r] += __shfl_xor(p1[r], off); p2[r] += __shfl_xor(p2[r], off); }
  }
  if (il == 0) {
#pragma unroll
    for (int r = 0; r < 4; ++r) {
      atomicAdd(&f1[r0 + kg * 4 + r], p1[r]);
      atomicAdd(&f2[r0 + kg * 4 + r], p2[r]);
    }
  }
#pragma unroll
  for (int t = 0; t < 3; ++t)
#pragma unroll
    for (int r = 0; r < 4; ++r)
      wtile[(kg * 4 + r) * 200 + (w * 3 + t) * 16 + il] = f2bf(acc[t][r]);
  __syncthreads();

  // pack 16x16x32 B-frags: 12 local ct tiles x 32 lanes = 384 items
  const int js = jg2 >> 1;
  const int lbase = (jg2 & 1) * 32;
#pragma unroll
  for (int rep = 0; rep < 2; ++rep) {
    const int flat = rep * 256 + tid;
    if (flat < 384) {
      const int ctl = flat >> 5;       // 0..11
      const int ll = flat & 31;        // 0..31
      const int l_g = lbase + ll;
      short8 v;
#pragma unroll
      for (int e = 0; e < 8; ++e) {
        const int jrow = (ll >> 4) * 8 + e;           // local j row 0..15
        v[e] = (short)wtile[jrow * 200 + ctl * 16 + (ll & 15)];
      }
      const int ctg = ch2 * 12 + ctl;
      *reinterpret_cast<short8*>((char*)whp +
          ((((size_t)b * 64 + js) * 24 + ctg) << 10) + l_g * 16) = v;
    }
  }
}

// ---------------- per-batch max of f2 + bf16-packed e2f2 table (8 KB/batch) ----------------
__global__ __launch_bounds__(256) void f2max_kernel(const float* __restrict__ f2,
                                                    float* __restrict__ gmax,
                                                    unsigned* __restrict__ etab) {
  __shared__ float wm[4];
  const int b = blockIdx.x;
  const int tid = threadIdx.x;
  float m = -3.0e38f;
  for (int i = tid; i < 2048; i += 256) {
    const float v = f2[b * 2048 + i];
    m = fmaxf(m, v);
    const unsigned e2 = f2bf(__expf(v));
    const unsigned q2 = f2bf(__expf(0.2f * v));
    etab[b * 2048 + i] = (e2 << 16) | q2;
  }
#pragma unroll
  for (int off = 32; off; off >>= 1) m = fmaxf(m, __shfl_xor(m, off));
  if ((tid & 63) == 0) wm[tid >> 6] = m;
  __syncthreads();
  if (tid == 0) gmax[b] = fmaxf(fmaxf(wm[0], wm[1]), fmaxf(wm[2], wm[3]));
}

// ---------------- Kernel E: attention v15 — cooperative-P LDS, zero redundancy ----------------
// grid 256: b = bi>>6, rg = bi&63 (32 rows). 512 thr = 8 waves = 2 rowhalves x 4 col-quarters.
// Per 32-j step: P-tile 32x32 built cooperatively (2 elems/thread, bf16 etab, no exp) into a
// 2 KB LDS A-frag (dbuf, 1 barrier/step); waves: A ds_read + 6 contiguous B-frags (depth-2) + 6 MFMA.
// Denominator completes in-block. 2 blocks/CU, 4 waves/SIMD.
__global__ __launch_bounds__(512, 4) void attn15_kernel(const float* __restrict__ f1,
                                                        const unsigned* __restrict__ etab,
                                                        const unsigned* __restrict__ adjm,
                                                        const unsigned short* __restrict__ whp,
                                                        const float* __restrict__ gmax,
                                                        float* __restrict__ out) {
  __shared__ __align__(16) char plds[4096 + 128];   // [2 bufs][2 h][64 lanes][16B] + drows
  float* drows = (float*)(plds + 4096);
  const int bi = blockIdx.x;
  const int b = bi >> 6, rg = bi & 63;
  const int tid = threadIdx.x;
  const int w = tid >> 6, lam = tid & 63;
  const int h = tid >> 8;              // rowhalf (== w>>2)
  const int q = w & 3;                 // col quarter (96 cols)
  const int mrem = tid & 255;
  const int lp = mrem >> 2, pair = mrem & 3;
  const int rowp = h * 16 + (lp & 15);
  const int igp = rg * 32 + rowp;
  const int jin = (lp >> 4) * 8 + pair * 2;

  if (tid < 32) drows[tid] = 0.f;

  const float f1v = f1[b * 2048 + igp];
  const float gm = gmax[b];
  const float mz = f1v + gm;
  const float mm = fmaxf(mz, 0.2f * mz);   // >= true masked row max (lrelu monotone)
  const float E1 = __expf(f1v - mm);
  const float F1 = __expf(0.2f * f1v - mm);
  const float T  = __expf(-f1v);           // z>0 <=> e^{f2} > e^{-f1}
  const unsigned* adjr = adjm + (size_t)igp * 64;
  const unsigned* etb = etab + b * 2048;
  char* pwr = plds + h * 1024 + lp * 16 + pair * 4;
  const char* prd = plds + h * 1024 + lam * 16;
  const char* wbase = (const char*)whp + ((((size_t)b * 64) * 24 + q * 6) << 10) + lam * 16;

  float dloc = 0.f;
  f32x4 acc[6];
#pragma unroll
  for (int t = 0; t < 6; ++t) acc[t] = (f32x4){0.f, 0.f, 0.f, 0.f};

#define PGEN(BUF, S)                                                                    \
  { const unsigned bits_ = adjr[S] >> jin;                                              \
    const uint2 tt_ = *reinterpret_cast<const uint2*>(etb + (S) * 32 + jin);            \
    const float e2a_ = __uint_as_float(tt_.x & 0xffff0000u);                            \
    const float q2a_ = __uint_as_float(tt_.x << 16);                                    \
    const bool pa_ = e2a_ > T;                                                          \
    float va_ = (pa_ ? e2a_ : q2a_) * (pa_ ? E1 : F1);                                  \
    va_ = (bits_ & 1u) ? va_ : 0.f;                                                     \
    const float e2b_ = __uint_as_float(tt_.y & 0xffff0000u);                            \
    const float q2b_ = __uint_as_float(tt_.y << 16);                                    \
    const bool pb_ = e2b_ > T;                                                          \
    float vb_ = (pb_ ? e2b_ : q2b_) * (pb_ ? E1 : F1);                                  \
    vb_ = (bits_ & 2u) ? vb_ : 0.f;                                                     \
    dloc += va_ + vb_;                                                                  \
    const unsigned pk_ = ((__float_as_uint(vb_) + 0x8000u) & 0xffff0000u) |             \
                         ((__float_as_uint(va_) + 0x8000u) >> 16);                      \
    *reinterpret_cast<unsigned*>(pwr + (BUF) * 2048) = pk_; }

#define LOADB(AR, S)                                                                    \
  { _Pragma("unroll")                                                                   \
    for (int tt = 0; tt < 6; ++tt)                                                      \
      AR[tt] = *reinterpret_cast<const short8*>(wbase + (((size_t)(S) * 24 + tt) << 10)); }

  short8 bA[6], bB[6];
  PGEN(0, 0)
  LOADB(bA, 0) LOADB(bB, 1)
  __syncthreads();

  for (int s = 0; s < 64; s += 2) {
    {
      short8 aF = *reinterpret_cast<const short8*>(prd);          // buf 0, step s
      PGEN(1, s + 1)
#pragma unroll
      for (int tt = 0; tt < 6; ++tt)
        acc[tt] = __builtin_amdgcn_mfma_f32_16x16x32_bf16(aF, bA[tt], acc[tt], 0, 0, 0);
      if (s + 2 < 64) LOADB(bA, s + 2)
      __syncthreads();
    }
    {
      short8 aG = *reinterpret_cast<const short8*>(prd + 2048);   // buf 1, step s+1
      if (s + 2 < 64) PGEN(0, s + 2)
#pragma unroll
      for (int tt = 0; tt < 6; ++tt)
        acc[tt] = __builtin_amdgcn_mfma_f32_16x16x32_bf16(aG, bB[tt], acc[tt], 0, 0, 0);
      if (s + 3 < 64) LOADB(bB, s + 3)
      __syncthreads();
    }
  }
#undef PGEN
#undef LOADB

  // ---- denominators (complete in-block) + epilogue ----
  dloc += __shfl_xor(dloc, 1);
  dloc += __shfl_xor(dloc, 2);
  if ((lam & 3) == 0) atomicAdd(&drows[rowp], dloc);
  __syncthreads();

  const size_t ob = ((size_t)b * 2048 + rg * 32) * 384 + q * 96;
#pragma unroll
  for (int tt = 0; tt < 6; ++tt) {
#pragma unroll
    for (int r = 0; r < 4; ++r) {
      const int row = h * 16 + (lam >> 4) * 4 + r;
      float v = acc[tt][r] / drows[row];
      v = v > 0.f ? v : expm1f(v);
      out[ob + (size_t)row * 384 + tt * 16 + (lam & 15)] = v;
    }
  }
}

extern "C" void kernel_launch(void* const* d_in, const int* in_sizes, int n_in,
                              void* d_out, int out_size, void* d_ws, size_t ws_size,
                              hipStream_t stream) {
  const float* x  = (const float*)d_in[0];
  const int* adj  = (const int*)d_in[1];
  const float* W  = (const float*)d_in[2];
  const float* a  = (const float*)d_in[3];
  const float* cw = (const float*)d_in[4];
  const float* cb = (const float*)d_in[5];
  float* out = (float*)d_out;

  char* ws = (char*)d_ws;
  unsigned short* wtp = (unsigned short*)ws; ws += (size_t)147456 * 2;    // packed W B-frags
  unsigned short* whp = (unsigned short*)ws; ws += (size_t)3145728 * 2;   // packed Wh 16x16x32 B-frags
  float* f1           = (float*)ws;          ws += (size_t)8192 * 4;
  float* f2           = (float*)ws;          ws += (size_t)8192 * 4;
  unsigned* adjm      = (unsigned*)ws;       ws += (size_t)2048 * 64 * 4;
  float* gmax         = (float*)ws;          ws += 64;
  unsigned* etab      = (unsigned*)ws;       ws += (size_t)8192 * 4;      // bf16(e^f2)|bf16(e^.2f2)

  pack_w_kernel<<<dim3(72), 256, 0, stream>>>(W, wtp);
  adjmask_kernel<<<dim3(16384), 256, 0, stream>>>(adj, adjm, f1);
  gemm_wh5_kernel<<<dim3(1024), 256, 0, stream>>>(x, cw, cb, wtp, a, whp, f1, f2);
  f2max_kernel<<<dim3(4), 256, 0, stream>>>(f2, gmax, etab);
  attn15_kernel<<<dim3(256), 512, 0, stream>>>(f1, etab, adjm, whp, gmax, out);
}

// Round 26
// 79.528 us; speedup vs baseline: 1.2835x; 1.2835x over previous
//
#include <hip/hip_runtime.h>

using short8 = __attribute__((ext_vector_type(8))) short;
using f32x4  = __attribute__((ext_vector_type(4))) float;
using f32x16 = __attribute__((ext_vector_type(16))) float;

__device__ __forceinline__ unsigned short f2bf(float f) {
  unsigned u = __float_as_uint(f);
  u += 0x7fffu + ((u >> 16) & 1u);
  return (unsigned short)(u >> 16);
}

// ---------------- pack W f32 [384k][384c] -> MFMA B-frag blobs wtp[kk 12][ct16 24][lane 64][8] ----------------
__global__ __launch_bounds__(256) void pack_w_kernel(const float* __restrict__ W,
                                                     unsigned short* __restrict__ wtp) {
  const int f = blockIdx.x * 4 + (threadIdx.x >> 6);   // 0..287
  const int l = threadIdx.x & 63;
  const int kk = f / 24, ct = f % 24;
  const int il = l & 15, kg = l >> 4;
  const float* src = W + (size_t)(kk * 32 + kg * 8) * 384 + ct * 16 + il;
  short8 v;
#pragma unroll
  for (int e = 0; e < 8; ++e) v[e] = (short)f2bf(src[(size_t)e * 384]);
  *reinterpret_cast<short8*>((char*)wtp + ((size_t)f << 10) + l * 16) = v;
}

// ---------------- adj int32 -> bitmask [2048][64] words (+ zero f1/f2) ----------------
__global__ __launch_bounds__(256) void adjmask_kernel(const int* __restrict__ adj,
                                                      unsigned* __restrict__ adjm,
                                                      float* __restrict__ f12) {
  if (blockIdx.x < 64) f12[blockIdx.x * 256 + threadIdx.x] = 0.f;   // f1+f2 (16384)
  const int wv = (blockIdx.x << 2) + (threadIdx.x >> 6);
  const int lane = threadIdx.x & 63;
  const int row = wv >> 5, j0 = (wv & 31) << 6;
  unsigned long long mask = __ballot(adj[(size_t)row * 2048 + j0 + lane] > 0);
  if (lane == 0) {
    adjm[row * 64 + (j0 >> 5)]     = (unsigned)mask;
    adjm[row * 64 + (j0 >> 5) + 1] = (unsigned)(mask >> 32);
  }
}

// ---------------- Kernel B: fused conv + Wh GEMM + pack + f1/f2 (16-row, col-split) ----------------
__global__ __launch_bounds__(256) void gemm_wh5_kernel(const float* __restrict__ x,
                                                       const float* __restrict__ cw,
                                                       const float* __restrict__ cb,
                                                       const unsigned short* __restrict__ wtp,
                                                       const float* __restrict__ a,
                                                       unsigned short* __restrict__ whp,
                                                       float* __restrict__ f1,
                                                       float* __restrict__ f2) {
  __shared__ __align__(16) char lds[24768 + 6400 + 1792];
  float* xin = (float*)lds;                                   // [12][516], 514 used
  unsigned short* atile = (unsigned short*)lds;               // [16][392]
  unsigned short* wtile = (unsigned short*)(lds + 24768);     // [16][200]
  float* cws = (float*)(lds + 24768 + 6400);                  // 432
  float* cbs = cws + 432;                                     // 12

  const int tid = threadIdx.x;
  const int rb = blockIdx.x;
  const int b = rb >> 8;
  const int jg2 = (rb >> 1) & 127;
  const int ch2 = rb & 1;
  const int r0 = ((b << 7) + jg2) << 4;
  const int w = tid >> 6, lane = tid & 63;
  const int il = lane & 15, kg = lane >> 4;

  for (int i = tid; i < 432; i += 256) cws[i] = cw[i];
  if (tid < 12) cbs[tid] = cb[tid];
  const float* xb = x + (size_t)b * 2048 * 12 * 32;
#pragma unroll
  for (int t = 0; t < 12; ++t) {
    for (int i = tid; i < 514; i += 256) {
      const int gp = jg2 * 512 + i - 1;
      float v = 0.f;
      if ((unsigned)gp < 65536u) v = xb[((size_t)(gp >> 5) * 12 + t) * 32 + (gp & 31)];
      xin[t * 516 + i] = v;
    }
  }
  __syncthreads();

  const int ploc = tid * 2;
  float accv0[12], accv1[12];
#pragma unroll
  for (int to = 0; to < 12; ++to) { accv0[to] = cbs[to]; accv1[to] = cbs[to]; }
#pragma unroll
  for (int ti = 0; ti < 12; ++ti) {
    const float x0 = xin[ti * 516 + ploc];
    const float x1 = xin[ti * 516 + ploc + 1];
    const float x2 = xin[ti * 516 + ploc + 2];
    const float x3 = xin[ti * 516 + ploc + 3];
#pragma unroll
    for (int to = 0; to < 12; ++to) {
      const float* wp = &cws[(to * 12 + ti) * 3];
      const float w0 = wp[0], w1 = wp[1], w2 = wp[2];
      accv0[to] += x0 * w0 + x1 * w1 + x2 * w2;
      accv1[to] += x1 * w0 + x2 * w1 + x3 * w2;
    }
  }
  __syncthreads();

  {
    const int row = ploc >> 5, f = ploc & 31;
    unsigned* ap32 = (unsigned*)(atile + row * 392 + f);
#pragma unroll
    for (int to = 0; to < 12; ++to) {
      const unsigned lo = f2bf(accv0[to]), hi = f2bf(accv1[to]);
      ap32[to * 16] = lo | (hi << 16);
    }
  }
  __syncthreads();

  f32x4 acc[3];
#pragma unroll
  for (int t = 0; t < 3; ++t) acc[t] = (f32x4){0.f, 0.f, 0.f, 0.f};
  const unsigned short* arow = atile + il * 392 + kg * 8;
  const int ct0 = ch2 * 12 + w * 3;
  const char* wb = (const char*)wtp + ((size_t)ct0 << 10) + lane * 16;

  short8 bcur[3], bnxt[3];
#pragma unroll
  for (int t = 0; t < 3; ++t)
    bcur[t] = *reinterpret_cast<const short8*>(wb + ((size_t)t << 10));
#pragma unroll
  for (int kk = 0; kk < 12; ++kk) {
    if (kk < 11) {
#pragma unroll
      for (int t = 0; t < 3; ++t)
        bnxt[t] = *reinterpret_cast<const short8*>(wb + (((size_t)(kk + 1) * 24 + t) << 10));
    }
    short8 af = *reinterpret_cast<const short8*>(arow + kk * 32);
#pragma unroll
    for (int t = 0; t < 3; ++t)
      acc[t] = __builtin_amdgcn_mfma_f32_16x16x32_bf16(af, bcur[t], acc[t], 0, 0, 0);
#pragma unroll
    for (int t = 0; t < 3; ++t) bcur[t] = bnxt[t];
  }

  float p1[4] = {0.f, 0.f, 0.f, 0.f}, p2[4] = {0.f, 0.f, 0.f, 0.f};
#pragma unroll
  for (int t = 0; t < 3; ++t) {
    const int c = (ct0 + t) * 16 + il;
    const float a1v = a[c], a2v = a[384 + c];
#pragma unroll
    for (int r = 0; r < 4; ++r) { p1[r] += acc[t][r] * a1v; p2[r] += acc[t][r] * a2v; }
  }
#pragma unroll
  for (int off = 1; off < 16; off <<= 1) {
#pragma unroll
    for (int r = 0; r < 4; ++r) { p1[r] += __shfl_xor(p1[r], off); p2[r] += __shfl_xor(p2[r], off); }
  }
  if (il == 0) {
#pragma unroll
    for (int r = 0; r < 4; ++r) {
      atomicAdd(&f1[r0 + kg * 4 + r], p1[r]);
      atomicAdd(&f2[r0 + kg * 4 + r], p2[r]);
    }
  }
#pragma unroll
  for (int t = 0; t < 3; ++t)
#pragma unroll
    for (int r = 0; r < 4; ++r)
      wtile[(kg * 4 + r) * 200 + (w * 3 + t) * 16 + il] = f2bf(acc[t][r]);
  __syncthreads();

#pragma unroll
  for (int rep = 0; rep < 2; ++rep) {
    const int flat = rep * 256 + tid;
    if (flat < 384) {
      const int ct32l = flat >> 6, l = flat & 63;
      const int l5 = l & 31, hw2 = l >> 5;
      short8 v;
#pragma unroll
      for (int e = 0; e < 8; ++e)
        v[e] = (short)wtile[(hw2 * 8 + e) * 200 + ct32l * 32 + l5];
      const int ct32g = ch2 * 6 + ct32l;
      *reinterpret_cast<short8*>((char*)whp +
          ((((size_t)b * 128 + jg2) * 12 + ct32g) << 10) + l * 16) = v;
    }
  }
}

// ---------------- per-batch max of f2 + bf16-packed exp table (8 KB/batch) ----------------
__global__ __launch_bounds__(256) void f2max_kernel(const float* __restrict__ f2,
                                                    float* __restrict__ gmax,
                                                    unsigned* __restrict__ etab) {
  __shared__ float wm[4];
  const int b = blockIdx.x;
  const int tid = threadIdx.x;
  float m = -3.0e38f;
  for (int i = tid; i < 2048; i += 256) {
    const float v = f2[b * 2048 + i];
    m = fmaxf(m, v);
    const unsigned e2 = f2bf(__expf(v));
    const unsigned q2 = f2bf(__expf(0.2f * v));
    etab[b * 2048 + i] = (e2 << 16) | q2;
  }
#pragma unroll
  for (int off = 32; off; off >>= 1) m = fmaxf(m, __shfl_xor(m, off));
  if ((tid & 63) == 0) wm[tid >> 6] = m;
  __syncthreads();
  if (tid == 0) gmax[b] = fmaxf(fmaxf(wm[0], wm[1]), fmaxf(wm[2], wm[3]));
}

// ---------------- Kernel E: attention v16 — attn13 structure, etab P-gen (no exp) ----------------
// grid 768: combo = bi%12 -> b = combo&3, ch = combo>>2 (128 cols); rg = bi/12 -> 32 rows.
// 4 waves = 4 ks (512 j each, 32 steps of 16 j, paired per adj word). Full depth-2.
__global__ __launch_bounds__(256, 3) void attn16_kernel(const float* __restrict__ f1,
                                                        const unsigned* __restrict__ etab,
                                                        const unsigned* __restrict__ adjm,
                                                        const unsigned short* __restrict__ whp,
                                                        const float* __restrict__ gmax,
                                                        float* __restrict__ out) {
  __shared__ float red[4][32][64];      // 32 KB
  __shared__ float dred[128];
  const int bi = blockIdx.x;
  const int combo = bi % 12;
  const int b  = combo & 3;
  const int ch = combo >> 2;            // 0..2
  const int i0 = (bi / 12) << 5;
  const int tid = threadIdx.x;
  const int ks = tid >> 6;
  const int lane = tid & 63;
  const int l5 = lane & 31, hw = lane >> 5;
  const int hw8 = hw * 8;
  const int ig = i0 + l5;

  const unsigned* adjr = adjm + (size_t)ig * 64 + ks * 16;   // 16 words = 512 j (2 steps/word)
  const unsigned* etb = etab + b * 2048 + ks * 512 + hw8;
  const char* pbase = (const char*)whp +
      ((((size_t)b * 128 + ks * 32) * 12 + ch * 4) << 10) + lane * 16;

  const float f1v = f1[b * 2048 + ig];
  const float gm = gmax[b];
  const float mz = f1v + gm;
  const float m  = fmaxf(mz, 0.2f * mz);     // >= true masked row max (lrelu monotone)
  const float E1 = __expf(f1v - m);
  const float F1 = __expf(0.2f * f1v - m);
  const float T  = __expf(-f1v);             // z>0 <=> e^{f2} > e^{-f1}

  const f32x16 zero16 = {0.f,0.f,0.f,0.f,0.f,0.f,0.f,0.f,0.f,0.f,0.f,0.f,0.f,0.f,0.f,0.f};
  f32x16 acc[4];
#pragma unroll
  for (int t = 0; t < 4; ++t) acc[t] = zero16;
  float denom = 0.f;

  short8 bA[4], bB[4];
  uint4 eA0, eA1, eB0, eB1;
  unsigned wC, wN;

#define LOADB(AR, KK)                                                                   \
  { _Pragma("unroll")                                                                   \
    for (int tt = 0; tt < 4; ++tt)                                                      \
      AR[tt] = *reinterpret_cast<const short8*>(pbase + (size_t)(KK) * 12288 +          \
                                                (size_t)tt * 1024); }

#define PELE(UW, BIT, DST)                                                              \
  { const float e2_ = __uint_as_float((UW) & 0xffff0000u);                              \
    const float q2_ = __uint_as_float((UW) << 16);                                      \
    const bool p_ = e2_ > T;                                                            \
    const float v_ = (p_ ? e2_ : q2_) * (p_ ? E1 : F1);                                 \
    DST = ((bits_ >> (BIT)) & 1u) ? v_ : 0.f; }

#define PKBF(HI, LO) (((__float_as_uint(HI) + 0x8000u) & 0xffff0000u) |                 \
                      ((__float_as_uint(LO) + 0x8000u) >> 16))

#define STEPD(AR, T0, T1, SH, KK, DL)                                                   \
  { const unsigned bits_ = wC >> ((SH) + hw8);                                          \
    float p0_, p1_, p2_, p3_, p4_, p5_, p6_, p7_;                                       \
    PELE(T0.x, 0, p0_)  PELE(T0.y, 1, p1_)  PELE(T0.z, 2, p2_)  PELE(T0.w, 3, p3_)      \
    PELE(T1.x, 4, p4_)  PELE(T1.y, 5, p5_)  PELE(T1.z, 6, p6_)  PELE(T1.w, 7, p7_)      \
    denom += (((p0_ + p1_) + (p2_ + p3_)) + ((p4_ + p5_) + (p6_ + p7_)));               \
    union { unsigned u[4]; short8 s8; } cc;                                             \
    cc.u[0] = PKBF(p1_, p0_); cc.u[1] = PKBF(p3_, p2_);                                 \
    cc.u[2] = PKBF(p5_, p4_); cc.u[3] = PKBF(p7_, p6_);                                 \
    _Pragma("unroll")                                                                   \
    for (int tt = 0; tt < 4; ++tt)                                                      \
      acc[tt] = __builtin_amdgcn_mfma_f32_32x32x16_bf16(cc.s8, AR[tt], acc[tt], 0, 0, 0); \
    if (DL) {                                                                           \
      LOADB(AR, (KK) + 2)                                                               \
      const unsigned* ep_ = etb + ((KK) + 2) * 16;                                      \
      T0 = *reinterpret_cast<const uint4*>(ep_);                                        \
      T1 = *reinterpret_cast<const uint4*>(ep_ + 4);                                    \
    } }

  // prologue
  LOADB(bA, 0) LOADB(bB, 1)
  eA0 = *reinterpret_cast<const uint4*>(etb);
  eA1 = *reinterpret_cast<const uint4*>(etb + 4);
  eB0 = *reinterpret_cast<const uint4*>(etb + 16);
  eB1 = *reinterpret_cast<const uint4*>(etb + 20);
  wC = adjr[0];
  wN = adjr[1];

  for (int t = 0; t < 16; ++t) {
    STEPD(bA, eA0, eA1, 0, 2 * t, (t < 15))
    STEPD(bB, eB0, eB1, 16, 2 * t + 1, (t < 15))
    wC = wN;
    wN = adjr[(t + 2 < 16) ? t + 2 : 15];
  }
#undef LOADB
#undef PELE
#undef PKBF
#undef STEPD

  // ---- epilogue: combine 4 ks accumulators via LDS, normalize, elu, store ----
  float dn = denom + __shfl_xor(denom, 32);   // sum over hw for this l5 row
  if (hw == 0) dred[ks * 32 + l5] = dn;

#pragma unroll
  for (int r = 0; r < 2; ++r) {
#pragma unroll
    for (int tt = 0; tt < 2; ++tt) {
#pragma unroll
      for (int q = 0; q < 16; ++q) {
        const int row = (q & 3) + 8 * (q >> 2) + 4 * hw;
        red[ks][row][tt * 32 + l5] = acc[r * 2 + tt][q];
      }
    }
    __syncthreads();
    const size_t ob = ((size_t)b * 2048 + i0) * 384 + ch * 128 + r * 64;
#pragma unroll
    for (int p = 0; p < 8; ++p) {
      const int idx = p * 256 + tid;
      const int row = idx >> 6;
      const int c = idx & 63;
      float v = red[0][row][c] + red[1][row][c] + red[2][row][c] + red[3][row][c];
      const float d = dred[row] + dred[32 + row] + dred[64 + row] + dred[96 + row];
      v /= d;
      v = v > 0.f ? v : expm1f(v);
      out[ob + (size_t)row * 384 + c] = v;
    }
    __syncthreads();
  }
}

extern "C" void kernel_launch(void* const* d_in, const int* in_sizes, int n_in,
                              void* d_out, int out_size, void* d_ws, size_t ws_size,
                              hipStream_t stream) {
  const float* x  = (const float*)d_in[0];
  const int* adj  = (const int*)d_in[1];
  const float* W  = (const float*)d_in[2];
  const float* a  = (const float*)d_in[3];
  const float* cw = (const float*)d_in[4];
  const float* cb = (const float*)d_in[5];
  float* out = (float*)d_out;

  char* ws = (char*)d_ws;
  unsigned short* wtp = (unsigned short*)ws; ws += (size_t)147456 * 2;    // packed W B-frags
  unsigned short* whp = (unsigned short*)ws; ws += (size_t)3145728 * 2;   // packed Wh B-frags [b][jstep][ct32]
  float* f1           = (float*)ws;          ws += (size_t)8192 * 4;
  float* f2           = (float*)ws;          ws += (size_t)8192 * 4;
  unsigned* adjm      = (unsigned*)ws;       ws += (size_t)2048 * 64 * 4;
  float* gmax         = (float*)ws;          ws += 64;
  unsigned* etab      = (unsigned*)ws;       ws += (size_t)8192 * 4;      // bf16(e^f2)|bf16(e^.2f2)

  pack_w_kernel<<<dim3(72), 256, 0, stream>>>(W, wtp);
  adjmask_kernel<<<dim3(16384), 256, 0, stream>>>(adj, adjm, f1);
  gemm_wh5_kernel<<<dim3(1024), 256, 0, stream>>>(x, cw, cb, wtp, a, whp, f1, f2);
  f2max_kernel<<<dim3(4), 256, 0, stream>>>(f2, gmax, etab);
  attn16_kernel<<<dim3(768), 256, 0, stream>>>(f1, etab, adjm, whp, gmax, out);
}

// Round 27
// 78.627 us; speedup vs baseline: 1.2982x; 1.0115x over previous
//
#include <hip/hip_runtime.h>

using short8 = __attribute__((ext_vector_type(8))) short;
using f32x4  = __attribute__((ext_vector_type(4))) float;
using f32x16 = __attribute__((ext_vector_type(16))) float;

__device__ __forceinline__ unsigned short f2bf(float f) {
  unsigned u = __float_as_uint(f);
  u += 0x7fffu + ((u >> 16) & 1u);
  return (unsigned short)(u >> 16);
}

// ---------------- pack W f32 [384k][384c] -> MFMA B-frag blobs wtp[kk 12][ct16 24][lane 64][8] ----------------
__global__ __launch_bounds__(256) void pack_w_kernel(const float* __restrict__ W,
                                                     unsigned short* __restrict__ wtp) {
  const int f = blockIdx.x * 4 + (threadIdx.x >> 6);   // 0..287
  const int l = threadIdx.x & 63;
  const int kk = f / 24, ct = f % 24;
  const int il = l & 15, kg = l >> 4;
  const float* src = W + (size_t)(kk * 32 + kg * 8) * 384 + ct * 16 + il;
  short8 v;
#pragma unroll
  for (int e = 0; e < 8; ++e) v[e] = (short)f2bf(src[(size_t)e * 384]);
  *reinterpret_cast<short8*>((char*)wtp + ((size_t)f << 10) + l * 16) = v;
}

// ---------------- adj int32 -> bitmask [2048][64] words (+ zero f1/f2) ----------------
__global__ __launch_bounds__(256) void adjmask_kernel(const int* __restrict__ adj,
                                                      unsigned* __restrict__ adjm,
                                                      float* __restrict__ f12) {
  if (blockIdx.x < 64) f12[blockIdx.x * 256 + threadIdx.x] = 0.f;   // f1+f2 (16384)
  const int wv = (blockIdx.x << 2) + (threadIdx.x >> 6);
  const int lane = threadIdx.x & 63;
  const int row = wv >> 5, j0 = (wv & 31) << 6;
  unsigned long long mask = __ballot(adj[(size_t)row * 2048 + j0 + lane] > 0);
  if (lane == 0) {
    adjm[row * 64 + (j0 >> 5)]     = (unsigned)mask;
    adjm[row * 64 + (j0 >> 5) + 1] = (unsigned)(mask >> 32);
  }
}

// ---------------- Kernel B: fused conv + Wh GEMM + pack + f1/f2 (16-row, col-split) ----------------
__global__ __launch_bounds__(256) void gemm_wh5_kernel(const float* __restrict__ x,
                                                       const float* __restrict__ cw,
                                                       const float* __restrict__ cb,
                                                       const unsigned short* __restrict__ wtp,
                                                       const float* __restrict__ a,
                                                       unsigned short* __restrict__ whp,
                                                       float* __restrict__ f1,
                                                       float* __restrict__ f2) {
  __shared__ __align__(16) char lds[24768 + 6400 + 1792];
  float* xin = (float*)lds;                                   // [12][516], 514 used
  unsigned short* atile = (unsigned short*)lds;               // [16][392]
  unsigned short* wtile = (unsigned short*)(lds + 24768);     // [16][200]
  float* cws = (float*)(lds + 24768 + 6400);                  // 432
  float* cbs = cws + 432;                                     // 12

  const int tid = threadIdx.x;
  const int rb = blockIdx.x;
  const int b = rb >> 8;
  const int jg2 = (rb >> 1) & 127;
  const int ch2 = rb & 1;
  const int r0 = ((b << 7) + jg2) << 4;
  const int w = tid >> 6, lane = tid & 63;
  const int il = lane & 15, kg = lane >> 4;

  for (int i = tid; i < 432; i += 256) cws[i] = cw[i];
  if (tid < 12) cbs[tid] = cb[tid];
  const float* xb = x + (size_t)b * 2048 * 12 * 32;
#pragma unroll
  for (int t = 0; t < 12; ++t) {
    for (int i = tid; i < 514; i += 256) {
      const int gp = jg2 * 512 + i - 1;
      float v = 0.f;
      if ((unsigned)gp < 65536u) v = xb[((size_t)(gp >> 5) * 12 + t) * 32 + (gp & 31)];
      xin[t * 516 + i] = v;
    }
  }
  __syncthreads();

  const int ploc = tid * 2;
  float accv0[12], accv1[12];
#pragma unroll
  for (int to = 0; to < 12; ++to) { accv0[to] = cbs[to]; accv1[to] = cbs[to]; }
#pragma unroll
  for (int ti = 0; ti < 12; ++ti) {
    const float x0 = xin[ti * 516 + ploc];
    const float x1 = xin[ti * 516 + ploc + 1];
    const float x2 = xin[ti * 516 + ploc + 2];
    const float x3 = xin[ti * 516 + ploc + 3];
#pragma unroll
    for (int to = 0; to < 12; ++to) {
      const float* wp = &cws[(to * 12 + ti) * 3];
      const float w0 = wp[0], w1 = wp[1], w2 = wp[2];
      accv0[to] += x0 * w0 + x1 * w1 + x2 * w2;
      accv1[to] += x1 * w0 + x2 * w1 + x3 * w2;
    }
  }
  __syncthreads();

  {
    const int row = ploc >> 5, f = ploc & 31;
    unsigned* ap32 = (unsigned*)(atile + row * 392 + f);
#pragma unroll
    for (int to = 0; to < 12; ++to) {
      const unsigned lo = f2bf(accv0[to]), hi = f2bf(accv1[to]);
      ap32[to * 16] = lo | (hi << 16);
    }
  }
  __syncthreads();

  f32x4 acc[3];
#pragma unroll
  for (int t = 0; t < 3; ++t) acc[t] = (f32x4){0.f, 0.f, 0.f, 0.f};
  const unsigned short* arow = atile + il * 392 + kg * 8;
  const int ct0 = ch2 * 12 + w * 3;
  const char* wb = (const char*)wtp + ((size_t)ct0 << 10) + lane * 16;

  short8 bcur[3], bnxt[3];
#pragma unroll
  for (int t = 0; t < 3; ++t)
    bcur[t] = *reinterpret_cast<const short8*>(wb + ((size_t)t << 10));
#pragma unroll
  for (int kk = 0; kk < 12; ++kk) {
    if (kk < 11) {
#pragma unroll
      for (int t = 0; t < 3; ++t)
        bnxt[t] = *reinterpret_cast<const short8*>(wb + (((size_t)(kk + 1) * 24 + t) << 10));
    }
    short8 af = *reinterpret_cast<const short8*>(arow + kk * 32);
#pragma unroll
    for (int t = 0; t < 3; ++t)
      acc[t] = __builtin_amdgcn_mfma_f32_16x16x32_bf16(af, bcur[t], acc[t], 0, 0, 0);
#pragma unroll
    for (int t = 0; t < 3; ++t) bcur[t] = bnxt[t];
  }

  float p1[4] = {0.f, 0.f, 0.f, 0.f}, p2[4] = {0.f, 0.f, 0.f, 0.f};
#pragma unroll
  for (int t = 0; t < 3; ++t) {
    const int c = (ct0 + t) * 16 + il;
    const float a1v = a[c], a2v = a[384 + c];
#pragma unroll
    for (int r = 0; r < 4; ++r) { p1[r] += acc[t][r] * a1v; p2[r] += acc[t][r] * a2v; }
  }
#pragma unroll
  for (int off = 1; off < 16; off <<= 1) {
#pragma unroll
    for (int r = 0; r < 4; ++r) { p1[r] += __shfl_xor(p1[r], off); p2[r] += __shfl_xor(p2[r], off); }
  }
  if (il == 0) {
#pragma unroll
    for (int r = 0; r < 4; ++r) {
      atomicAdd(&f1[r0 + kg * 4 + r], p1[r]);
      atomicAdd(&f2[r0 + kg * 4 + r], p2[r]);
    }
  }
#pragma unroll
  for (int t = 0; t < 3; ++t)
#pragma unroll
    for (int r = 0; r < 4; ++r)
      wtile[(kg * 4 + r) * 200 + (w * 3 + t) * 16 + il] = f2bf(acc[t][r]);
  __syncthreads();

#pragma unroll
  for (int rep = 0; rep < 2; ++rep) {
    const int flat = rep * 256 + tid;
    if (flat < 384) {
      const int ct32l = flat >> 6, l = flat & 63;
      const int l5 = l & 31, hw2 = l >> 5;
      short8 v;
#pragma unroll
      for (int e = 0; e < 8; ++e)
        v[e] = (short)wtile[(hw2 * 8 + e) * 200 + ct32l * 32 + l5];
      const int ct32g = ch2 * 6 + ct32l;
      *reinterpret_cast<short8*>((char*)whp +
          ((((size_t)b * 128 + jg2) * 12 + ct32g) << 10) + l * 16) = v;
    }
  }
}

// ---------------- etab: bf16(e^f2) | bf16(e^{0.2 f2}) per (b,j) — 8 KB/batch ----------------
__global__ __launch_bounds__(256) void etab_kernel(const float* __restrict__ f2,
                                                   unsigned* __restrict__ etab) {
  const int b = blockIdx.x;
  const int tid = threadIdx.x;
  for (int i = tid; i < 2048; i += 256) {
    const float v = f2[b * 2048 + i];
    const unsigned e2 = f2bf(__expf(v));
    const unsigned q2 = f2bf(__expf(0.2f * v));
    etab[b * 2048 + i] = (e2 << 16) | q2;
  }
}

// ---------------- Kernel E: attention v17 — E1-cancelled softmax (no m/gmax), etab P-gen ----------------
// grid 768: combo = bi%12 -> b = combo&3, ch = combo>>2 (128 cols); rg = bi/12 -> 32 rows.
// P = E1*Q with Q = mask*(e2>T ? e2 : R*q2); E1 cancels in Q/sum(Q). 6-op PELE.
__global__ __launch_bounds__(256, 3) void attn17_kernel(const float* __restrict__ f1,
                                                        const unsigned* __restrict__ etab,
                                                        const unsigned* __restrict__ adjm,
                                                        const unsigned short* __restrict__ whp,
                                                        float* __restrict__ out) {
  __shared__ float red[4][32][64];      // 32 KB
  __shared__ float dred[128];
  const int bi = blockIdx.x;
  const int combo = bi % 12;
  const int b  = combo & 3;
  const int ch = combo >> 2;            // 0..2
  const int i0 = (bi / 12) << 5;
  const int tid = threadIdx.x;
  const int ks = tid >> 6;
  const int lane = tid & 63;
  const int l5 = lane & 31, hw = lane >> 5;
  const int hw8 = hw * 8;
  const int ig = i0 + l5;

  const unsigned* adjr = adjm + (size_t)ig * 64 + ks * 16;   // 16 words = 512 j (2 steps/word)
  const unsigned* etb = etab + b * 2048 + ks * 512 + hw8;
  const char* pbase = (const char*)whp +
      ((((size_t)b * 128 + ks * 32) * 12 + ch * 4) << 10) + lane * 16;

  const float f1v = f1[b * 2048 + ig];
  const float T = __expf(-f1v);          // z>0 <=> e^{f2} > e^{-f1}
  const float R = __expf(-0.8f * f1v);   // F1/E1

  const f32x16 zero16 = {0.f,0.f,0.f,0.f,0.f,0.f,0.f,0.f,0.f,0.f,0.f,0.f,0.f,0.f,0.f,0.f};
  f32x16 acc[4];
#pragma unroll
  for (int t = 0; t < 4; ++t) acc[t] = zero16;
  float denom = 0.f;

  short8 bA[4], bB[4];
  uint4 eA0, eA1, eB0, eB1;
  unsigned wC, wN;

#define LOADB(AR, KK)                                                                   \
  { _Pragma("unroll")                                                                   \
    for (int tt = 0; tt < 4; ++tt)                                                      \
      AR[tt] = *reinterpret_cast<const short8*>(pbase + (size_t)(KK) * 12288 +          \
                                                (size_t)tt * 1024); }

#define PELE(UW, BIT, DST)                                                              \
  { const float e2_ = __uint_as_float((UW) & 0xffff0000u);                              \
    const float q2_ = __uint_as_float((UW) << 16);                                      \
    const float v_ = (e2_ > T) ? e2_ : R * q2_;                                         \
    DST = ((bits_ >> (BIT)) & 1u) ? v_ : 0.f; }

#define PKBF(HI, LO) (((__float_as_uint(HI) + 0x8000u) & 0xffff0000u) |                 \
                      ((__float_as_uint(LO) + 0x8000u) >> 16))

#define STEPD(AR, T0, T1, SH, KK, DL)                                                   \
  { const unsigned bits_ = wC >> ((SH) + hw8);                                          \
    float p0_, p1_, p2_, p3_, p4_, p5_, p6_, p7_;                                       \
    PELE(T0.x, 0, p0_)  PELE(T0.y, 1, p1_)  PELE(T0.z, 2, p2_)  PELE(T0.w, 3, p3_)      \
    PELE(T1.x, 4, p4_)  PELE(T1.y, 5, p5_)  PELE(T1.z, 6, p6_)  PELE(T1.w, 7, p7_)      \
    denom += (((p0_ + p1_) + (p2_ + p3_)) + ((p4_ + p5_) + (p6_ + p7_)));               \
    union { unsigned u[4]; short8 s8; } cc;                                             \
    cc.u[0] = PKBF(p1_, p0_); cc.u[1] = PKBF(p3_, p2_);                                 \
    cc.u[2] = PKBF(p5_, p4_); cc.u[3] = PKBF(p7_, p6_);                                 \
    _Pragma("unroll")                                                                   \
    for (int tt = 0; tt < 4; ++tt)                                                      \
      acc[tt] = __builtin_amdgcn_mfma_f32_32x32x16_bf16(cc.s8, AR[tt], acc[tt], 0, 0, 0); \
    if (DL) {                                                                           \
      LOADB(AR, (KK) + 2)                                                               \
      const unsigned* ep_ = etb + ((KK) + 2) * 16;                                      \
      T0 = *reinterpret_cast<const uint4*>(ep_);                                        \
      T1 = *reinterpret_cast<const uint4*>(ep_ + 4);                                    \
    } }

  // prologue
  LOADB(bA, 0) LOADB(bB, 1)
  eA0 = *reinterpret_cast<const uint4*>(etb);
  eA1 = *reinterpret_cast<const uint4*>(etb + 4);
  eB0 = *reinterpret_cast<const uint4*>(etb + 16);
  eB1 = *reinterpret_cast<const uint4*>(etb + 20);
  wC = adjr[0];
  wN = adjr[1];

  for (int t = 0; t < 16; ++t) {
    STEPD(bA, eA0, eA1, 0, 2 * t, (t < 15))
    STEPD(bB, eB0, eB1, 16, 2 * t + 1, (t < 15))
    wC = wN;
    wN = adjr[(t + 2 < 16) ? t + 2 : 15];
  }
#undef LOADB
#undef PELE
#undef PKBF
#undef STEPD

  // ---- epilogue: combine 4 ks accumulators via LDS, normalize, elu, store ----
  float dn = denom + __shfl_xor(denom, 32);   // sum over hw for this l5 row
  if (hw == 0) dred[ks * 32 + l5] = dn;

#pragma unroll
  for (int r = 0; r < 2; ++r) {
#pragma unroll
    for (int tt = 0; tt < 2; ++tt) {
#pragma unroll
      for (int q = 0; q < 16; ++q) {
        const int row = (q & 3) + 8 * (q >> 2) + 4 * hw;
        red[ks][row][tt * 32 + l5] = acc[r * 2 + tt][q];
      }
    }
    __syncthreads();
    const size_t ob = ((size_t)b * 2048 + i0) * 384 + ch * 128 + r * 64;
#pragma unroll
    for (int p = 0; p < 8; ++p) {
      const int idx = p * 256 + tid;
      const int row = idx >> 6;
      const int c = idx & 63;
      float v = red[0][row][c] + red[1][row][c] + red[2][row][c] + red[3][row][c];
      const float d = dred[row] + dred[32 + row] + dred[64 + row] + dred[96 + row];
      v /= d;
      v = v > 0.f ? v : expm1f(v);
      out[ob + (size_t)row * 384 + c] = v;
    }
    __syncthreads();
  }
}

extern "C" void kernel_launch(void* const* d_in, const int* in_sizes, int n_in,
                              void* d_out, int out_size, void* d_ws, size_t ws_size,
                              hipStream_t stream) {
  const float* x  = (const float*)d_in[0];
  const int* adj  = (const int*)d_in[1];
  const float* W  = (const float*)d_in[2];
  const float* a  = (const float*)d_in[3];
  const float* cw = (const float*)d_in[4];
  const float* cb = (const float*)d_in[5];
  float* out = (float*)d_out;

  char* ws = (char*)d_ws;
  unsigned short* wtp = (unsigned short*)ws; ws += (size_t)147456 * 2;    // packed W B-frags
  unsigned short* whp = (unsigned short*)ws; ws += (size_t)3145728 * 2;   // packed Wh B-frags [b][jstep][ct32]
  float* f1           = (float*)ws;          ws += (size_t)8192 * 4;
  float* f2           = (float*)ws;          ws += (size_t)8192 * 4;
  unsigned* adjm      = (unsigned*)ws;       ws += (size_t)2048 * 64 * 4;
  unsigned* etab      = (unsigned*)ws;       ws += (size_t)8192 * 4;      // bf16(e^f2)|bf16(e^.2f2)

  pack_w_kernel<<<dim3(72), 256, 0, stream>>>(W, wtp);
  adjmask_kernel<<<dim3(16384), 256, 0, stream>>>(adj, adjm, f1);
  gemm_wh5_kernel<<<dim3(1024), 256, 0, stream>>>(x, cw, cb, wtp, a, whp, f1, f2);
  etab_kernel<<<dim3(4), 256, 0, stream>>>(f2, etab);
  attn17_kernel<<<dim3(768), 256, 0, stream>>>(f1, etab, adjm, whp, out);
}

// Round 28
// 75.975 us; speedup vs baseline: 1.3435x; 1.0349x over previous
//
#include <hip/hip_runtime.h>

using short8 = __attribute__((ext_vector_type(8))) short;
using f32x4  = __attribute__((ext_vector_type(4))) float;
using f32x16 = __attribute__((ext_vector_type(16))) float;

__device__ __forceinline__ unsigned short f2bf(float f) {
  unsigned u = __float_as_uint(f);
  u += 0x7fffu + ((u >> 16) & 1u);
  return (unsigned short)(u >> 16);
}

// ---------------- pack W f32 [384k][384c] -> MFMA B-frag blobs wtp[kk 12][ct16 24][lane 64][8] ----------------
__global__ __launch_bounds__(256) void pack_w_kernel(const float* __restrict__ W,
                                                     unsigned short* __restrict__ wtp) {
  const int f = blockIdx.x * 4 + (threadIdx.x >> 6);   // 0..287
  const int l = threadIdx.x & 63;
  const int kk = f / 24, ct = f % 24;
  const int il = l & 15, kg = l >> 4;
  const float* src = W + (size_t)(kk * 32 + kg * 8) * 384 + ct * 16 + il;
  short8 v;
#pragma unroll
  for (int e = 0; e < 8; ++e) v[e] = (short)f2bf(src[(size_t)e * 384]);
  *reinterpret_cast<short8*>((char*)wtp + ((size_t)f << 10) + l * 16) = v;
}

// ---------------- adj int32 -> bitmask [2048][64] words ----------------
__global__ __launch_bounds__(256) void adjmask_kernel(const int* __restrict__ adj,
                                                      unsigned* __restrict__ adjm) {
  const int wv = (blockIdx.x << 2) + (threadIdx.x >> 6);
  const int lane = threadIdx.x & 63;
  const int row = wv >> 5, j0 = (wv & 31) << 6;
  unsigned long long mask = __ballot(adj[(size_t)row * 2048 + j0 + lane] > 0);
  if (lane == 0) {
    adjm[row * 64 + (j0 >> 5)]     = (unsigned)mask;
    adjm[row * 64 + (j0 >> 5) + 1] = (unsigned)(mask >> 32);
  }
}

// ---------------- Kernel B: fused conv + Wh GEMM + pack + f1/f2 (16 rows, FULL 384 cols) ----------------
// grid 512: b = rb>>7, jg2 = rb&127 -> rows jg2*16..+16. 256 thr = 4 waves (96 cols each).
// whp[b][jstep 128][ct32 12][lane 64][8]: lane l elem e = Wh[b][jstep*16+(l>>5)*8+e][ct32*32+(l&31)]
__global__ __launch_bounds__(256) void gemm_wh6_kernel(const float* __restrict__ x,
                                                       const float* __restrict__ cw,
                                                       const float* __restrict__ cb,
                                                       const unsigned short* __restrict__ wtp,
                                                       const float* __restrict__ a,
                                                       unsigned short* __restrict__ whp,
                                                       float* __restrict__ f1,
                                                       float* __restrict__ f2) {
  __shared__ __align__(16) char lds[24768 + 12544 + 1792 + 128];
  float* xin = (float*)lds;                                   // [12][516], 514 used
  unsigned short* atile = (unsigned short*)lds;               // [16][392] (after conv, overlaps xin)
  unsigned short* wtile = (unsigned short*)(lds + 24768);     // [16][392]
  float* cws = (float*)(lds + 24768 + 12544);                 // 432
  float* cbs = cws + 432;                                     // 12
  float* s1s = (float*)(lds + 24768 + 12544 + 1792);          // 16
  float* s2s = s1s + 16;                                      // 16

  const int tid = threadIdx.x;
  const int rb = blockIdx.x;
  const int b = rb >> 7, jg2 = rb & 127;
  const int r0 = rb << 4;
  const int w = tid >> 6, lane = tid & 63;
  const int il = lane & 15, kg = lane >> 4;

  for (int i = tid; i < 432; i += 256) cws[i] = cw[i];
  if (tid < 12) cbs[tid] = cb[tid];
  if (tid < 16) { s1s[tid] = 0.f; s2s[tid] = 0.f; }
  const float* xb = x + (size_t)b * 2048 * 12 * 32;
#pragma unroll
  for (int t = 0; t < 12; ++t) {
    for (int i = tid; i < 514; i += 256) {
      const int gp = jg2 * 512 + i - 1;
      float v = 0.f;
      if ((unsigned)gp < 65536u) v = xb[((size_t)(gp >> 5) * 12 + t) * 32 + (gp & 31)];
      xin[t * 516 + i] = v;
    }
  }

  // B-frag prologue: independent of LDS; issued early so loads ride under the conv phase
  const int ct0 = w * 6;
  const char* wb = (const char*)wtp + ((size_t)ct0 << 10) + lane * 16;
  short8 bcur[6], bnxt[6];
#pragma unroll
  for (int t = 0; t < 6; ++t)
    bcur[t] = *reinterpret_cast<const short8*>(wb + ((size_t)t << 10));

  __syncthreads();

  // conv: each thread 2 positions x 12 t_o
  const int ploc = tid * 2;
  float accv0[12], accv1[12];
#pragma unroll
  for (int to = 0; to < 12; ++to) { accv0[to] = cbs[to]; accv1[to] = cbs[to]; }
#pragma unroll
  for (int ti = 0; ti < 12; ++ti) {
    const float x0 = xin[ti * 516 + ploc];
    const float x1 = xin[ti * 516 + ploc + 1];
    const float x2 = xin[ti * 516 + ploc + 2];
    const float x3 = xin[ti * 516 + ploc + 3];
#pragma unroll
    for (int to = 0; to < 12; ++to) {
      const float* wp = &cws[(to * 12 + ti) * 3];
      const float w0 = wp[0], w1 = wp[1], w2 = wp[2];
      accv0[to] += x0 * w0 + x1 * w1 + x2 * w2;
      accv1[to] += x1 * w0 + x2 * w1 + x3 * w2;
    }
  }
  __syncthreads();   // all xin reads done before atile overwrite

  {
    const int row = ploc >> 5, f = ploc & 31;
    unsigned* ap32 = (unsigned*)(atile + row * 392 + f);
#pragma unroll
    for (int to = 0; to < 12; ++to) {
      const unsigned lo = f2bf(accv0[to]), hi = f2bf(accv1[to]);
      ap32[to * 16] = lo | (hi << 16);
    }
  }
  __syncthreads();

  // MFMA: 16 rows x 96 cols per wave; contiguous wtp B-frags, depth-2 over kk
  f32x4 acc[6];
#pragma unroll
  for (int t = 0; t < 6; ++t) acc[t] = (f32x4){0.f, 0.f, 0.f, 0.f};
  const unsigned short* arow = atile + il * 392 + kg * 8;
#pragma unroll
  for (int kk = 0; kk < 12; ++kk) {
    if (kk < 11) {
#pragma unroll
      for (int t = 0; t < 6; ++t)
        bnxt[t] = *reinterpret_cast<const short8*>(wb + (((size_t)(kk + 1) * 24 + t) << 10));
    }
    short8 af = *reinterpret_cast<const short8*>(arow + kk * 32);
#pragma unroll
    for (int t = 0; t < 6; ++t)
      acc[t] = __builtin_amdgcn_mfma_f32_16x16x32_bf16(af, bcur[t], acc[t], 0, 0, 0);
#pragma unroll
    for (int t = 0; t < 6; ++t) bcur[t] = bnxt[t];
  }

  // fused f1/f2 (complete in-block; LDS atomics)
  float p1[4] = {0.f, 0.f, 0.f, 0.f}, p2[4] = {0.f, 0.f, 0.f, 0.f};
#pragma unroll
  for (int t = 0; t < 6; ++t) {
    const int c = (ct0 + t) * 16 + il;
    const float a1v = a[c], a2v = a[384 + c];
#pragma unroll
    for (int r = 0; r < 4; ++r) { p1[r] += acc[t][r] * a1v; p2[r] += acc[t][r] * a2v; }
  }
#pragma unroll
  for (int off = 1; off < 16; off <<= 1) {
#pragma unroll
    for (int r = 0; r < 4; ++r) { p1[r] += __shfl_xor(p1[r], off); p2[r] += __shfl_xor(p2[r], off); }
  }
  if (il == 0) {
#pragma unroll
    for (int r = 0; r < 4; ++r) {
      atomicAdd(&s1s[kg * 4 + r], p1[r]);
      atomicAdd(&s2s[kg * 4 + r], p2[r]);
    }
  }
#pragma unroll
  for (int t = 0; t < 6; ++t)
#pragma unroll
    for (int r = 0; r < 4; ++r)
      wtile[(kg * 4 + r) * 392 + (ct0 + t) * 16 + il] = f2bf(acc[t][r]);
  __syncthreads();

  // pack 32x32x16 B-frags: 12 ct32 tiles x 64 lanes = 768 items, 3 reps x 256
#pragma unroll
  for (int rep = 0; rep < 3; ++rep) {
    const int flat = rep * 256 + tid;
    const int ct32 = flat >> 6, l = flat & 63;
    const int l5 = l & 31, hw2 = l >> 5;
    short8 v;
#pragma unroll
    for (int e = 0; e < 8; ++e)
      v[e] = (short)wtile[(hw2 * 8 + e) * 392 + ct32 * 32 + l5];
    *reinterpret_cast<short8*>((char*)whp +
        ((((size_t)b * 128 + jg2) * 12 + ct32) << 10) + l * 16) = v;
  }
  if (tid < 16) { f1[r0 + tid] = s1s[tid]; f2[r0 + tid] = s2s[tid]; }
}

// ---------------- etab: bf16(e^f2) | bf16(e^{0.2 f2}) per (b,j) — 8 KB/batch ----------------
__global__ __launch_bounds__(256) void etab_kernel(const float* __restrict__ f2,
                                                   unsigned* __restrict__ etab) {
  const int b = blockIdx.x;
  const int tid = threadIdx.x;
  for (int i = tid; i < 2048; i += 256) {
    const float v = f2[b * 2048 + i];
    const unsigned e2 = f2bf(__expf(v));
    const unsigned q2 = f2bf(__expf(0.2f * v));
    etab[b * 2048 + i] = (e2 << 16) | q2;
  }
}

// ---------------- Kernel E: attention v17 — E1-cancelled softmax, etab P-gen ----------------
// grid 768: combo = bi%12 -> b = combo&3, ch = combo>>2 (128 cols); rg = bi/12 -> 32 rows.
// P = E1*Q with Q = mask*(e2>T ? e2 : R*q2); E1 cancels in Q/sum(Q).
__global__ __launch_bounds__(256, 3) void attn17_kernel(const float* __restrict__ f1,
                                                        const unsigned* __restrict__ etab,
                                                        const unsigned* __restrict__ adjm,
                                                        const unsigned short* __restrict__ whp,
                                                        float* __restrict__ out) {
  __shared__ float red[4][32][64];      // 32 KB
  __shared__ float dred[128];
  const int bi = blockIdx.x;
  const int combo = bi % 12;
  const int b  = combo & 3;
  const int ch = combo >> 2;            // 0..2
  const int i0 = (bi / 12) << 5;
  const int tid = threadIdx.x;
  const int ks = tid >> 6;
  const int lane = tid & 63;
  const int l5 = lane & 31, hw = lane >> 5;
  const int hw8 = hw * 8;
  const int ig = i0 + l5;

  const unsigned* adjr = adjm + (size_t)ig * 64 + ks * 16;   // 16 words = 512 j (2 steps/word)
  const unsigned* etb = etab + b * 2048 + ks * 512 + hw8;
  const char* pbase = (const char*)whp +
      ((((size_t)b * 128 + ks * 32) * 12 + ch * 4) << 10) + lane * 16;

  const float f1v = f1[b * 2048 + ig];
  const float T = __expf(-f1v);          // z>0 <=> e^{f2} > e^{-f1}
  const float R = __expf(-0.8f * f1v);   // F1/E1

  const f32x16 zero16 = {0.f,0.f,0.f,0.f,0.f,0.f,0.f,0.f,0.f,0.f,0.f,0.f,0.f,0.f,0.f,0.f};
  f32x16 acc[4];
#pragma unroll
  for (int t = 0; t < 4; ++t) acc[t] = zero16;
  float denom = 0.f;

  short8 bA[4], bB[4];
  uint4 eA0, eA1, eB0, eB1;
  unsigned wC, wN;

#define LOADB(AR, KK)                                                                   \
  { _Pragma("unroll")                                                                   \
    for (int tt = 0; tt < 4; ++tt)                                                      \
      AR[tt] = *reinterpret_cast<const short8*>(pbase + (size_t)(KK) * 12288 +          \
                                                (size_t)tt * 1024); }

#define PELE(UW, BIT, DST)                                                              \
  { const float e2_ = __uint_as_float((UW) & 0xffff0000u);                              \
    const float q2_ = __uint_as_float((UW) << 16);                                      \
    const float v_ = (e2_ > T) ? e2_ : R * q2_;                                         \
    DST = ((bits_ >> (BIT)) & 1u) ? v_ : 0.f; }

#define PKBF(HI, LO) (((__float_as_uint(HI) + 0x8000u) & 0xffff0000u) |                 \
                      ((__float_as_uint(LO) + 0x8000u) >> 16))

#define STEPD(AR, T0, T1, SH, KK, DL)                                                   \
  { const unsigned bits_ = wC >> ((SH) + hw8);                                          \
    float p0_, p1_, p2_, p3_, p4_, p5_, p6_, p7_;                                       \
    PELE(T0.x, 0, p0_)  PELE(T0.y, 1, p1_)  PELE(T0.z, 2, p2_)  PELE(T0.w, 3, p3_)      \
    PELE(T1.x, 4, p4_)  PELE(T1.y, 5, p5_)  PELE(T1.z, 6, p6_)  PELE(T1.w, 7, p7_)      \
    denom += (((p0_ + p1_) + (p2_ + p3_)) + ((p4_ + p5_) + (p6_ + p7_)));               \
    union { unsigned u[4]; short8 s8; } cc;                                             \
    cc.u[0] = PKBF(p1_, p0_); cc.u[1] = PKBF(p3_, p2_);                                 \
    cc.u[2] = PKBF(p5_, p4_); cc.u[3] = PKBF(p7_, p6_);                                 \
    _Pragma("unroll")                                                                   \
    for (int tt = 0; tt < 4; ++tt)                                                      \
      acc[tt] = __builtin_amdgcn_mfma_f32_32x32x16_bf16(cc.s8, AR[tt], acc[tt], 0, 0, 0); \
    if (DL) {                                                                           \
      LOADB(AR, (KK) + 2)                                                               \
      const unsigned* ep_ = etb + ((KK) + 2) * 16;                                      \
      T0 = *reinterpret_cast<const uint4*>(ep_);                                        \
      T1 = *reinterpret_cast<const uint4*>(ep_ + 4);                                    \
    } }

  // prologue
  LOADB(bA, 0) LOADB(bB, 1)
  eA0 = *reinterpret_cast<const uint4*>(etb);
  eA1 = *reinterpret_cast<const uint4*>(etb + 4);
  eB0 = *reinterpret_cast<const uint4*>(etb + 16);
  eB1 = *reinterpret_cast<const uint4*>(etb + 20);
  wC = adjr[0];
  wN = adjr[1];

  for (int t = 0; t < 16; ++t) {
    STEPD(bA, eA0, eA1, 0, 2 * t, (t < 15))
    STEPD(bB, eB0, eB1, 16, 2 * t + 1, (t < 15))
    wC = wN;
    wN = adjr[(t + 2 < 16) ? t + 2 : 15];
  }
#undef LOADB
#undef PELE
#undef PKBF
#undef STEPD

  // ---- epilogue: combine 4 ks accumulators via LDS, normalize, elu, store ----
  float dn = denom + __shfl_xor(denom, 32);   // sum over hw for this l5 row
  if (hw == 0) dred[ks * 32 + l5] = dn;

#pragma unroll
  for (int r = 0; r < 2; ++r) {
#pragma unroll
    for (int tt = 0; tt < 2; ++tt) {
#pragma unroll
      for (int q = 0; q < 16; ++q) {
        const int row = (q & 3) + 8 * (q >> 2) + 4 * hw;
        red[ks][row][tt * 32 + l5] = acc[r * 2 + tt][q];
      }
    }
    __syncthreads();
    const size_t ob = ((size_t)b * 2048 + i0) * 384 + ch * 128 + r * 64;
#pragma unroll
    for (int p = 0; p < 8; ++p) {
      const int idx = p * 256 + tid;
      const int row = idx >> 6;
      const int c = idx & 63;
      float v = red[0][row][c] + red[1][row][c] + red[2][row][c] + red[3][row][c];
      const float d = dred[row] + dred[32 + row] + dred[64 + row] + dred[96 + row];
      v /= d;
      v = v > 0.f ? v : expm1f(v);
      out[ob + (size_t)row * 384 + c] = v;
    }
    __syncthreads();
  }
}

extern "C" void kernel_launch(void* const* d_in, const int* in_sizes, int n_in,
                              void* d_out, int out_size, void* d_ws, size_t ws_size,
                              hipStream_t stream) {
  const float* x  = (const float*)d_in[0];
  const int* adj  = (const int*)d_in[1];
  const float* W  = (const float*)d_in[2];
  const float* a  = (const float*)d_in[3];
  const float* cw = (const float*)d_in[4];
  const float* cb = (const float*)d_in[5];
  float* out = (float*)d_out;

  char* ws = (char*)d_ws;
  unsigned short* wtp = (unsigned short*)ws; ws += (size_t)147456 * 2;    // packed W B-frags
  unsigned short* whp = (unsigned short*)ws; ws += (size_t)3145728 * 2;   // packed Wh B-frags [b][jstep][ct32]
  float* f1           = (float*)ws;          ws += (size_t)8192 * 4;
  float* f2           = (float*)ws;          ws += (size_t)8192 * 4;
  unsigned* adjm      = (unsigned*)ws;       ws += (size_t)2048 * 64 * 4;
  unsigned* etab      = (unsigned*)ws;       ws += (size_t)8192 * 4;      // bf16(e^f2)|bf16(e^.2f2)

  pack_w_kernel<<<dim3(72), 256, 0, stream>>>(W, wtp);
  adjmask_kernel<<<dim3(16384), 256, 0, stream>>>(adj, adjm);
  gemm_wh6_kernel<<<dim3(512), 256, 0, stream>>>(x, cw, cb, wtp, a, whp, f1, f2);
  etab_kernel<<<dim3(4), 256, 0, stream>>>(f2, etab);
  attn17_kernel<<<dim3(768), 256, 0, stream>>>(f1, etab, adjm, whp, out);
}